// Round 13
// baseline (144.569 us; speedup 1.0000x reference)
//
#include <hip/hip_runtime.h>

#define N_NODES 50000
#define N_EDGES 500000
#define IN_C 128
#define HID_C 128
#define OUT_C 64

#define SCAN_NB 196            // (50000+255)/256
#define NTILES 782             // (50000+63)/64
#define FILLB 256              // fill blocks fused into gemm1 dispatch
#define SP 136                 // padded LDS row stride (shorts)

typedef short s16x8 __attribute__((ext_vector_type(8)));
typedef float f32x4 __attribute__((ext_vector_type(4)));

__device__ __forceinline__ unsigned short f2bf(float f) {
    unsigned int u = __float_as_uint(f);
    u = (u + 0x7FFF + ((u >> 16) & 1)) >> 16;  // round-to-nearest-even
    return (unsigned short)u;
}
__device__ __forceinline__ float bf2f(unsigned short u) {
    return __uint_as_float(((unsigned int)u) << 16);
}

// ---------------- zero ----------------

__global__ __launch_bounds__(256) void zero_kernel(int4* __restrict__ p, int n4) {
    int i = blockIdx.x * blockDim.x + threadIdx.x;
    if (i < n4) p[i] = make_int4(0, 0, 0, 0);
}

// ---------------- CSR build ----------------

__global__ void deg_kernel(const int* __restrict__ dst, int* __restrict__ degi) {
    int e = blockIdx.x * blockDim.x + threadIdx.x;
    if (e < N_EDGES) atomicAdd(&degi[dst[e]], 1);
}

__global__ __launch_bounds__(256) void scan1_kernel(const int* __restrict__ degi,
                                                    int* __restrict__ rowptr,
                                                    int* __restrict__ blocksum,
                                                    float* __restrict__ dinv) {
    __shared__ int sh[256];
    const int t = threadIdx.x;
    const int i = blockIdx.x * 256 + t;
    int v = (i < N_NODES) ? degi[i] : 0;
    sh[t] = v;
    __syncthreads();
#pragma unroll
    for (int off = 1; off < 256; off <<= 1) {
        int tmp = (t >= off) ? sh[t - off] : 0;
        __syncthreads();
        sh[t] += tmp;
        __syncthreads();
    }
    if (i < N_NODES) {
        rowptr[i] = sh[t];
        dinv[i] = rsqrtf((float)v + 1.0f);
    }
    if (t == 255) blocksum[blockIdx.x] = sh[255];
}

__global__ __launch_bounds__(256) void scan23_kernel(int* __restrict__ rowptr,
                                                     int* __restrict__ degi,
                                                     const int* __restrict__ blocksum) {
    __shared__ int sh[256];
    const int t = threadIdx.x;
    int v = (t < SCAN_NB) ? blocksum[t] : 0;
    sh[t] = v;
    __syncthreads();
#pragma unroll
    for (int off = 1; off < 256; off <<= 1) {
        int tmp = (t >= off) ? sh[t - off] : 0;
        __syncthreads();
        sh[t] += tmp;
        __syncthreads();
    }
    const int myoff = sh[blockIdx.x] - blocksum[blockIdx.x];
    const int i = blockIdx.x * 256 + t;
    if (i < N_NODES) {
        int d = degi[i];
        int ex = rowptr[i] - d + myoff;
        rowptr[i] = ex;
        degi[i] = ex;  // cursor for fill
    }
    if (i == 0) rowptr[N_NODES] = N_EDGES;
}

// ---------------- GEMM1 (prescaled h1) FUSED with CSR fill (role-split) ----------------
// Blocks [0,NTILES): h1[n,128](bf16) = dinv[n] * (x[n,128] @ W1). Blocks >= NTILES: fill.
// Independent work: gemm1 needs x/W1/dinv; fill needs scan23's cursor. Both ~12-14us -> one
// dispatch, fill fully hidden.

__global__ __launch_bounds__(256) void gemm1_fill_kernel(const float* __restrict__ x,
                                                         const float* __restrict__ W,
                                                         const float* __restrict__ dinv,
                                                         unsigned short* __restrict__ H,
                                                         const int* __restrict__ src,
                                                         const int* __restrict__ dst,
                                                         int* __restrict__ cursor,
                                                         int* __restrict__ csr) {
    constexpr int NOUT = HID_C;
    constexpr int NT = NOUT / 64;
    __shared__ unsigned short Xl[64 * SP];
    const int tid = threadIdx.x;

    if (blockIdx.x >= NTILES) {
        for (int e = (blockIdx.x - NTILES) * 256 + tid; e < N_EDGES; e += FILLB * 256) {
            int d = dst[e];
            int pos = atomicAdd(&cursor[d], 1);
            csr[pos] = src[e];
        }
        return;
    }

    const int w = tid >> 6;
    const int lane = tid & 63;
    const int kk = lane >> 4;
    const int cl = lane & 15;
    const int row0 = blockIdx.x * 64;

    for (int c = tid; c < 64 * 32; c += 256) {
        int r = c >> 5, cc = c & 31;
        int gr = row0 + r;
        ushort4 o;
        if (gr < N_NODES) {
            float4 v = ((const float4*)x)[(size_t)gr * 32 + cc];
            o = make_ushort4(f2bf(v.x), f2bf(v.y), f2bf(v.z), f2bf(v.w));
        } else {
            o = make_ushort4(0, 0, 0, 0);
        }
        *(ushort4*)&Xl[r * SP + cc * 4] = o;
    }

    s16x8 bfrag[NT][4];
#pragma unroll
    for (int i = 0; i < NT; i++) {
        int colg = (w * NT + i) * 16 + cl;
#pragma unroll
        for (int s = 0; s < 4; s++)
#pragma unroll
            for (int j = 0; j < 8; j++)
                bfrag[i][s][j] = (short)f2bf(W[(s * 32 + kk * 8 + j) * NOUT + colg]);
    }

    __syncthreads();

    f32x4 acc[4][NT];
#pragma unroll
    for (int rt = 0; rt < 4; rt++)
#pragma unroll
        for (int i = 0; i < NT; i++) acc[rt][i] = (f32x4){0.f, 0.f, 0.f, 0.f};

#pragma unroll
    for (int rt = 0; rt < 4; rt++) {
        const int rl = rt * 16 + cl;
        s16x8 a[4];
#pragma unroll
        for (int s = 0; s < 4; s++)
            a[s] = *(const s16x8*)&Xl[rl * SP + s * 32 + kk * 8];
#pragma unroll
        for (int i = 0; i < NT; i++)
#pragma unroll
            for (int s = 0; s < 4; s++)
                acc[rt][i] = __builtin_amdgcn_mfma_f32_16x16x32_bf16(a[s], bfrag[i][s],
                                                                     acc[rt][i], 0, 0, 0);
    }

#pragma unroll
    for (int rt = 0; rt < 4; rt++) {
        float4 dv = *(const float4*)&dinv[row0 + rt * 16 + kk * 4];
        float dvv[4] = {dv.x, dv.y, dv.z, dv.w};
#pragma unroll
        for (int i = 0; i < NT; i++) {
            int colg = (w * NT + i) * 16 + cl;
#pragma unroll
            for (int r = 0; r < 4; r++) {
                int rowg = row0 + rt * 16 + kk * 4 + r;
                if (rowg < N_NODES)
                    H[(size_t)rowg * NOUT + colg] = f2bf(dvv[r] * acc[rt][i][r]);
            }
        }
    }
}

// ---------------- FUSED agg layer1 + GEMM2: one block = 64 nodes ----------------
// Phase A: 4 waves x 16 nodes; per node the agg128 half-wave gather over prescaled h1;
//          relu'd h2 row written to LDS (padded GEMM layout) as bf16. NO h2 global traffic.
// Phase B: gemm2 tile from the LDS h2 -> h3[n,64](bf16, prescaled by dinv).
// Row-local dependency only (C row r depends only on A row r), so no grid sync needed.

__global__ __launch_bounds__(256) void agg1_gemm2_kernel(const int* __restrict__ rowptr,
                                                         const int* __restrict__ csr,
                                                         const float* __restrict__ dinv,
                                                         const uint2* __restrict__ H,  // h1'
                                                         const float* __restrict__ b1,
                                                         const float* __restrict__ W2,
                                                         unsigned short* __restrict__ h3) {
    constexpr int NOUT = OUT_C;
    __shared__ unsigned short Xl[64 * SP];

    const int tid = threadIdx.x;
    const int w = tid >> 6;
    const int half = (tid >> 5) & 1;
    const int q = tid & 31;
    const int row0 = blockIdx.x * 64;

    // ---- Phase A: aggregate 16 nodes per wave into the LDS tile ----
    for (int i = 0; i < 16; i++) {
        const int r = w * 16 + i;          // tile row
        const int node = row0 + r;
        if (node >= N_NODES) break;

        float a0 = 0.f, a1 = 0.f, a2 = 0.f, a3 = 0.f;
        const int e0 = rowptr[node];
        const int cnt = rowptr[node + 1] - e0;
        const int base = e0 + half * 4;

        int k = 0;
        for (; k + 8 <= cnt; k += 8) {  // 8 edges/iter, 4 per half
            int i0 = csr[base + k];
            int i1 = csr[base + k + 1];
            int i2 = csr[base + k + 2];
            int i3 = csr[base + k + 3];
            uint2 h0 = H[(size_t)i0 * 32 + q];
            uint2 h1v = H[(size_t)i1 * 32 + q];
            uint2 h2v = H[(size_t)i2 * 32 + q];
            uint2 h3v = H[(size_t)i3 * 32 + q];
            a0 += bf2f((unsigned short)(h0.x & 0xffff)) + bf2f((unsigned short)(h1v.x & 0xffff)) +
                  bf2f((unsigned short)(h2v.x & 0xffff)) + bf2f((unsigned short)(h3v.x & 0xffff));
            a1 += bf2f((unsigned short)(h0.x >> 16)) + bf2f((unsigned short)(h1v.x >> 16)) +
                  bf2f((unsigned short)(h2v.x >> 16)) + bf2f((unsigned short)(h3v.x >> 16));
            a2 += bf2f((unsigned short)(h0.y & 0xffff)) + bf2f((unsigned short)(h1v.y & 0xffff)) +
                  bf2f((unsigned short)(h2v.y & 0xffff)) + bf2f((unsigned short)(h3v.y & 0xffff));
            a3 += bf2f((unsigned short)(h0.y >> 16)) + bf2f((unsigned short)(h1v.y >> 16)) +
                  bf2f((unsigned short)(h2v.y >> 16)) + bf2f((unsigned short)(h3v.y >> 16));
        }
        for (int j = k + half; j < cnt; j += 2) {  // tail: 1 edge per half per iter
            int s = csr[e0 + j];
            uint2 h = H[(size_t)s * 32 + q];
            a0 += bf2f((unsigned short)(h.x & 0xffff));
            a1 += bf2f((unsigned short)(h.x >> 16));
            a2 += bf2f((unsigned short)(h.y & 0xffff));
            a3 += bf2f((unsigned short)(h.y >> 16));
        }

        a0 += __shfl_xor(a0, 32);
        a1 += __shfl_xor(a1, 32);
        a2 += __shfl_xor(a2, 32);
        a3 += __shfl_xor(a3, 32);

        if (half == 0) {
            const float dn = dinv[node];
            uint2 self = H[(size_t)node * 32 + q];
            float4 bb = *(const float4*)&b1[q * 4];
            float r0 = fmaf(dn, bf2f((unsigned short)(self.x & 0xffff)) + a0, bb.x);
            float r1 = fmaf(dn, bf2f((unsigned short)(self.x >> 16)) + a1, bb.y);
            float r2 = fmaf(dn, bf2f((unsigned short)(self.y & 0xffff)) + a2, bb.z);
            float r3 = fmaf(dn, bf2f((unsigned short)(self.y >> 16)) + a3, bb.w);
            r0 = fmaxf(r0, 0.f);
            r1 = fmaxf(r1, 0.f);
            r2 = fmaxf(r2, 0.f);
            r3 = fmaxf(r3, 0.f);
            ushort4 o = make_ushort4(f2bf(r0), f2bf(r1), f2bf(r2), f2bf(r3));
            *(ushort4*)&Xl[r * SP + q * 4] = o;  // h2 row directly in GEMM layout
        }
    }

    __syncthreads();

    // ---- Phase B: gemm2 tile (64x128 @ 128x64) from LDS ----
    const int lane = tid & 63;
    const int kk = lane >> 4;
    const int cl = lane & 15;

    s16x8 bfrag[4];
#pragma unroll
    for (int s = 0; s < 4; s++)
#pragma unroll
        for (int j = 0; j < 8; j++)
            bfrag[s][j] = (short)f2bf(W2[(s * 32 + kk * 8 + j) * NOUT + w * 16 + cl]);

    f32x4 acc[4];
#pragma unroll
    for (int rt = 0; rt < 4; rt++) acc[rt] = (f32x4){0.f, 0.f, 0.f, 0.f};

#pragma unroll
    for (int rt = 0; rt < 4; rt++) {
        const int rl = rt * 16 + cl;
        s16x8 a[4];
#pragma unroll
        for (int s = 0; s < 4; s++)
            a[s] = *(const s16x8*)&Xl[rl * SP + s * 32 + kk * 8];
#pragma unroll
        for (int s = 0; s < 4; s++)
            acc[rt] = __builtin_amdgcn_mfma_f32_16x16x32_bf16(a[s], bfrag[s], acc[rt], 0, 0, 0);
    }

#pragma unroll
    for (int rt = 0; rt < 4; rt++) {
        float4 dv = *(const float4*)&dinv[row0 + rt * 16 + kk * 4];
        float dvv[4] = {dv.x, dv.y, dv.z, dv.w};
        int colg = w * 16 + cl;
#pragma unroll
        for (int r = 0; r < 4; r++) {
            int rowg = row0 + rt * 16 + kk * 4 + r;
            if (rowg < N_NODES)
                h3[(size_t)rowg * NOUT + colg] = f2bf(dvv[r] * acc[rt][r]);
        }
    }
}

// ---------------- agg layer 2 (64 ch, h3 PRE-SCALED): 1 node/wave, fp32 out ----------------

__global__ __launch_bounds__(256) void agg64_kernel(const int* __restrict__ rowptr,
                                                    const int* __restrict__ csr,
                                                    const float* __restrict__ dinv,
                                                    const unsigned int* __restrict__ H,
                                                    const float* __restrict__ b,
                                                    float2* __restrict__ out) {
    const int node = blockIdx.x * 4 + (threadIdx.x >> 6);
    const int half = (threadIdx.x >> 5) & 1;
    const int q = threadIdx.x & 31;

    float a0 = 0.f, a1 = 0.f;
    const int e0 = rowptr[node];
    const int cnt = rowptr[node + 1] - e0;
    const int base = e0 + half * 4;

    int k = 0;
    for (; k + 8 <= cnt; k += 8) {
        int i0 = csr[base + k];
        int i1 = csr[base + k + 1];
        int i2 = csr[base + k + 2];
        int i3 = csr[base + k + 3];
        unsigned int h0 = H[(size_t)i0 * 32 + q];
        unsigned int h1 = H[(size_t)i1 * 32 + q];
        unsigned int h2 = H[(size_t)i2 * 32 + q];
        unsigned int h3 = H[(size_t)i3 * 32 + q];
        a0 += bf2f((unsigned short)(h0 & 0xffff)) + bf2f((unsigned short)(h1 & 0xffff)) +
              bf2f((unsigned short)(h2 & 0xffff)) + bf2f((unsigned short)(h3 & 0xffff));
        a1 += bf2f((unsigned short)(h0 >> 16)) + bf2f((unsigned short)(h1 >> 16)) +
              bf2f((unsigned short)(h2 >> 16)) + bf2f((unsigned short)(h3 >> 16));
    }
    for (int j = k + half; j < cnt; j += 2) {
        int s = csr[e0 + j];
        unsigned int h = H[(size_t)s * 32 + q];
        a0 += bf2f((unsigned short)(h & 0xffff));
        a1 += bf2f((unsigned short)(h >> 16));
    }

    a0 += __shfl_xor(a0, 32);
    a1 += __shfl_xor(a1, 32);

    if (half == 0) {
        const float dn = dinv[node];
        unsigned int self = H[(size_t)node * 32 + q];
        float2 bb = *(const float2*)&b[q * 2];
        float r0 = fmaf(dn, bf2f((unsigned short)(self & 0xffff)) + a0, bb.x);
        float r1 = fmaf(dn, bf2f((unsigned short)(self >> 16)) + a1, bb.y);
        out[(size_t)node * 32 + q] = make_float2(r0, r1);
    }
}

// ---------------- launch ----------------

extern "C" void kernel_launch(void* const* d_in, const int* in_sizes, int n_in,
                              void* d_out, int out_size, void* d_ws, size_t ws_size,
                              hipStream_t stream) {
    const float* x  = (const float*)d_in[0];
    const int*   ei = (const int*)d_in[1];
    const float* W1 = (const float*)d_in[2];
    const float* b1 = (const float*)d_in[3];
    const float* W2 = (const float*)d_in[4];
    const float* b2 = (const float*)d_in[5];

    const int* src = ei;
    const int* dst = ei + N_EDGES;

    // workspace layout
    unsigned short* h1 = (unsigned short*)d_ws;                 // [N][128] bf16 (prescaled h1')
    unsigned short* h3 = h1 + (size_t)N_NODES * HID_C;          // [N][64]  bf16 (prescaled h3')
    float* dinv   = (float*)(h3 + (size_t)N_NODES * OUT_C);     // 50,048 f
    int*   degi   = (int*)(dinv + 50048);                       // 50,048 i (deg -> cursor)
    int*   rowptr = degi + 50048;                               // 50,001 i
    int*   csr    = rowptr + 50051;                             // 500,000 i
    int*   bsum   = csr + 500000;                               // 256 i

    // 1) zero degree array
    {
        int n4 = (N_NODES + 3) / 4;
        zero_kernel<<<(n4 + 255) / 256, 256, 0, stream>>>((int4*)degi, n4);
    }
    // 2) degree histogram
    deg_kernel<<<(N_EDGES + 255) / 256, 256, 0, stream>>>(dst, degi);
    // 3-4) scan -> rowptr, dinv, cursor
    scan1_kernel<<<SCAN_NB, 256, 0, stream>>>(degi, rowptr, bsum, dinv);
    scan23_kernel<<<SCAN_NB, 256, 0, stream>>>(rowptr, degi, bsum);
    // 5) GEMM1 (prescaled h1') || CSR fill — role-split fused
    gemm1_fill_kernel<<<NTILES + FILLB, 256, 0, stream>>>(x, W1, dinv, h1, src, dst, degi, csr);
    // 6) agg layer1 + GEMM2 fused (h2 lives only in LDS) -> h3'
    agg1_gemm2_kernel<<<NTILES, 256, 0, stream>>>(rowptr, csr, dinv, (const uint2*)h1, b1, W2,
                                                  h3);
    // 7) agg layer 2 -> out (fp32)
    agg64_kernel<<<N_NODES / 4, 256, 0, stream>>>(rowptr, csr, dinv, (const unsigned int*)h3,
                                                  b2, (float2*)d_out);
}

// Round 14
// 139.264 us; speedup vs baseline: 1.0381x; 1.0381x over previous
//
#include <hip/hip_runtime.h>

#define N_NODES 50000
#define N_EDGES 500000
#define IN_C 128
#define HID_C 128
#define OUT_C 64

#define SCAN_NB 196            // (50000+255)/256
#define NTILES 782             // (50000+63)/64
#define DEGB 256               // histogram blocks fused into gemm1 dispatch
#define SP 136                 // padded LDS row stride (shorts)

#define AGG_F (1u << 30)
#define PRE_F (1u << 31)
#define VAL_M ((1u << 30) - 1)

typedef short s16x8 __attribute__((ext_vector_type(8)));
typedef float f32x4 __attribute__((ext_vector_type(4)));

__device__ __forceinline__ unsigned short f2bf(float f) {
    unsigned int u = __float_as_uint(f);
    u = (u + 0x7FFF + ((u >> 16) & 1)) >> 16;  // round-to-nearest-even
    return (unsigned short)u;
}
__device__ __forceinline__ float bf2f(unsigned short u) {
    return __uint_as_float(((unsigned int)u) << 16);
}

// ---------------- zero (degi + lookback state in one dispatch) ----------------

__global__ __launch_bounds__(256) void zero2_kernel(int4* __restrict__ a, int n4a,
                                                    int4* __restrict__ b, int n4b) {
    int i = blockIdx.x * blockDim.x + threadIdx.x;
    if (i < n4a) a[i] = make_int4(0, 0, 0, 0);
    if (i < n4b) b[i] = make_int4(0, 0, 0, 0);
}

// ---------------- single-pass scan (decoupled lookback) ----------------
// Replaces scan1+scan23. 196 blocks, all co-resident (<256 CUs) -> spin is deadlock-free.
// state[b] packs value|flag in one 32b word; atomicExch publish / atomicAdd(,0) read are
// device-scope, bridging per-XCD L2 non-coherence. Writes rowptr (exclusive), cursor, dinv.

__global__ __launch_bounds__(256) void scanall_kernel(const int* __restrict__ degi,
                                                      int* __restrict__ rowptr,
                                                      int* __restrict__ cursor,
                                                      float* __restrict__ dinv,
                                                      unsigned int* __restrict__ state) {
    __shared__ int sh[256];
    __shared__ unsigned int sprefix;
    const int t = threadIdx.x;
    const int b = blockIdx.x;
    const int i = b * 256 + t;
    int v = (i < N_NODES) ? degi[i] : 0;
    sh[t] = v;
    __syncthreads();
#pragma unroll
    for (int off = 1; off < 256; off <<= 1) {
        int tmp = (t >= off) ? sh[t - off] : 0;
        __syncthreads();
        sh[t] += tmp;
        __syncthreads();
    }
    if (t == 0) {
        const unsigned int agg = (unsigned int)sh[255];
        atomicExch(&state[b], agg | AGG_F);  // publish aggregate
        unsigned int run = 0;
        for (int p = b - 1; p >= 0;) {       // lookback
            unsigned int s;
            do { s = atomicAdd(&state[p], 0u); } while (s == 0u);
            run += s & VAL_M;
            if (s & PRE_F) break;
            p--;
        }
        atomicExch(&state[b], (run + agg) | PRE_F);  // publish inclusive prefix
        sprefix = run;
    }
    __syncthreads();
    const int run = (int)sprefix;
    if (i < N_NODES) {
        int ex = run + sh[t] - v;  // global exclusive prefix
        rowptr[i] = ex;
        cursor[i] = ex;
        dinv[i] = rsqrtf((float)v + 1.0f);
    }
    if (i == 0) rowptr[N_NODES] = N_EDGES;
}

__global__ void fill_kernel(const int* __restrict__ src, const int* __restrict__ dst,
                            int* __restrict__ cursor, int* __restrict__ csr_src) {
    int e = blockIdx.x * blockDim.x + threadIdx.x;
    if (e < N_EDGES) {
        int d = dst[e];
        int pos = atomicAdd(&cursor[d], 1);
        csr_src[pos] = src[e];
    }
}

// ---------------- MFMA GEMM: H[n,NOUT](bf16) = (X[n,128] @ W[128,NOUT]) * (dinv?) ----------------
// DEG_FUSE: blocks >= NTILES instead run the degree histogram (independent work).

template <int NOUT, bool XBF16, bool PRESCALE, bool DEG_FUSE>
__global__ __launch_bounds__(256) void mfma_gemm(const void* __restrict__ Xv,
                                                 const float* __restrict__ W,
                                                 const float* __restrict__ dinv,
                                                 unsigned short* __restrict__ H,
                                                 const int* __restrict__ dst,
                                                 int* __restrict__ degi) {
    constexpr int NT = NOUT / 64;
    __shared__ unsigned short Xl[64 * SP];

    const int tid = threadIdx.x;

    if (DEG_FUSE && blockIdx.x >= NTILES) {
        for (int e = (blockIdx.x - NTILES) * 256 + tid; e < N_EDGES; e += DEGB * 256)
            atomicAdd(&degi[dst[e]], 1);
        return;
    }

    const int w = tid >> 6;
    const int lane = tid & 63;
    const int kk = lane >> 4;
    const int cl = lane & 15;
    const int row0 = blockIdx.x * 64;

    for (int c = tid; c < 64 * 32; c += 256) {
        int r = c >> 5, cc = c & 31;
        int gr = row0 + r;
        ushort4 o;
        if (XBF16) {
            o = (gr < N_NODES) ? ((const ushort4*)Xv)[(size_t)gr * 32 + cc]
                               : make_ushort4(0, 0, 0, 0);
        } else {
            if (gr < N_NODES) {
                float4 v = ((const float4*)Xv)[(size_t)gr * 32 + cc];
                o = make_ushort4(f2bf(v.x), f2bf(v.y), f2bf(v.z), f2bf(v.w));
            } else {
                o = make_ushort4(0, 0, 0, 0);
            }
        }
        *(ushort4*)&Xl[r * SP + cc * 4] = o;
    }

    s16x8 bfrag[NT][4];
#pragma unroll
    for (int i = 0; i < NT; i++) {
        int colg = (w * NT + i) * 16 + cl;
#pragma unroll
        for (int s = 0; s < 4; s++)
#pragma unroll
            for (int j = 0; j < 8; j++)
                bfrag[i][s][j] = (short)f2bf(W[(s * 32 + kk * 8 + j) * NOUT + colg]);
    }

    __syncthreads();

    f32x4 acc[4][NT];
#pragma unroll
    for (int rt = 0; rt < 4; rt++)
#pragma unroll
        for (int i = 0; i < NT; i++) acc[rt][i] = (f32x4){0.f, 0.f, 0.f, 0.f};

#pragma unroll
    for (int rt = 0; rt < 4; rt++) {
        const int rl = rt * 16 + cl;
        s16x8 a[4];
#pragma unroll
        for (int s = 0; s < 4; s++)
            a[s] = *(const s16x8*)&Xl[rl * SP + s * 32 + kk * 8];
#pragma unroll
        for (int i = 0; i < NT; i++)
#pragma unroll
            for (int s = 0; s < 4; s++)
                acc[rt][i] = __builtin_amdgcn_mfma_f32_16x16x32_bf16(a[s], bfrag[i][s],
                                                                     acc[rt][i], 0, 0, 0);
    }

#pragma unroll
    for (int rt = 0; rt < 4; rt++) {
        float dvv[4] = {1.f, 1.f, 1.f, 1.f};
        if (PRESCALE) {
            float4 dv = *(const float4*)&dinv[row0 + rt * 16 + kk * 4];
            dvv[0] = dv.x; dvv[1] = dv.y; dvv[2] = dv.z; dvv[3] = dv.w;
        }
#pragma unroll
        for (int i = 0; i < NT; i++) {
            int colg = (w * NT + i) * 16 + cl;
#pragma unroll
            for (int r = 0; r < 4; r++) {
                int rowg = row0 + rt * 16 + kk * 4 + r;
                if (rowg < N_NODES)
                    H[(size_t)rowg * NOUT + colg] = f2bf(dvv[r] * acc[rt][i][r]);
            }
        }
    }
}

// ---------------- agg layer 1 (128 ch, UNSCALED h1): 1 node/wave, per-edge dinv ----------------
// out[n][c] = relu( dinv[n]*( dinv[n]*h1[n][c] + sum_s dinv[s]*h1[s][c] ) + b[c] )

__global__ __launch_bounds__(256) void agg128_kernel(const int* __restrict__ rowptr,
                                                     const int* __restrict__ csr,
                                                     const float* __restrict__ dinv,
                                                     const uint2* __restrict__ H,
                                                     const float* __restrict__ b,
                                                     uint2* __restrict__ out) {
    const int node = blockIdx.x * 4 + (threadIdx.x >> 6);
    const int half = (threadIdx.x >> 5) & 1;
    const int q = threadIdx.x & 31;

    float a0 = 0.f, a1 = 0.f, a2 = 0.f, a3 = 0.f;
    const int e0 = rowptr[node];
    const int cnt = rowptr[node + 1] - e0;
    const int base = e0 + half * 4;

    int k = 0;
    for (; k + 8 <= cnt; k += 8) {  // 8 edges/iter, 4 per half
        int i0 = csr[base + k];
        int i1 = csr[base + k + 1];
        int i2 = csr[base + k + 2];
        int i3 = csr[base + k + 3];
        float d0 = dinv[i0], d1 = dinv[i1], d2 = dinv[i2], d3 = dinv[i3];
        uint2 h0 = H[(size_t)i0 * 32 + q];
        uint2 h1v = H[(size_t)i1 * 32 + q];
        uint2 h2v = H[(size_t)i2 * 32 + q];
        uint2 h3v = H[(size_t)i3 * 32 + q];
        a0 = fmaf(d0, bf2f((unsigned short)(h0.x & 0xffff)), a0);
        a1 = fmaf(d0, bf2f((unsigned short)(h0.x >> 16)), a1);
        a2 = fmaf(d0, bf2f((unsigned short)(h0.y & 0xffff)), a2);
        a3 = fmaf(d0, bf2f((unsigned short)(h0.y >> 16)), a3);
        a0 = fmaf(d1, bf2f((unsigned short)(h1v.x & 0xffff)), a0);
        a1 = fmaf(d1, bf2f((unsigned short)(h1v.x >> 16)), a1);
        a2 = fmaf(d1, bf2f((unsigned short)(h1v.y & 0xffff)), a2);
        a3 = fmaf(d1, bf2f((unsigned short)(h1v.y >> 16)), a3);
        a0 = fmaf(d2, bf2f((unsigned short)(h2v.x & 0xffff)), a0);
        a1 = fmaf(d2, bf2f((unsigned short)(h2v.x >> 16)), a1);
        a2 = fmaf(d2, bf2f((unsigned short)(h2v.y & 0xffff)), a2);
        a3 = fmaf(d2, bf2f((unsigned short)(h2v.y >> 16)), a3);
        a0 = fmaf(d3, bf2f((unsigned short)(h3v.x & 0xffff)), a0);
        a1 = fmaf(d3, bf2f((unsigned short)(h3v.x >> 16)), a1);
        a2 = fmaf(d3, bf2f((unsigned short)(h3v.y & 0xffff)), a2);
        a3 = fmaf(d3, bf2f((unsigned short)(h3v.y >> 16)), a3);
    }
    for (int j = k + half; j < cnt; j += 2) {  // tail: 2 edges/iter (1 per half)
        int s = csr[e0 + j];
        float ds = dinv[s];
        uint2 h = H[(size_t)s * 32 + q];
        a0 = fmaf(ds, bf2f((unsigned short)(h.x & 0xffff)), a0);
        a1 = fmaf(ds, bf2f((unsigned short)(h.x >> 16)), a1);
        a2 = fmaf(ds, bf2f((unsigned short)(h.y & 0xffff)), a2);
        a3 = fmaf(ds, bf2f((unsigned short)(h.y >> 16)), a3);
    }

    a0 += __shfl_xor(a0, 32);
    a1 += __shfl_xor(a1, 32);
    a2 += __shfl_xor(a2, 32);
    a3 += __shfl_xor(a3, 32);

    if (half == 0) {
        const float dn = dinv[node];
        uint2 self = H[(size_t)node * 32 + q];
        float4 bb = *(const float4*)&b[q * 4];
        float r0 = fmaf(dn, fmaf(dn, bf2f((unsigned short)(self.x & 0xffff)), a0), bb.x);
        float r1 = fmaf(dn, fmaf(dn, bf2f((unsigned short)(self.x >> 16)), a1), bb.y);
        float r2 = fmaf(dn, fmaf(dn, bf2f((unsigned short)(self.y & 0xffff)), a2), bb.z);
        float r3 = fmaf(dn, fmaf(dn, bf2f((unsigned short)(self.y >> 16)), a3), bb.w);
        r0 = fmaxf(r0, 0.f);
        r1 = fmaxf(r1, 0.f);
        r2 = fmaxf(r2, 0.f);
        r3 = fmaxf(r3, 0.f);
        uint2 o;
        o.x = (unsigned int)f2bf(r0) | ((unsigned int)f2bf(r1) << 16);
        o.y = (unsigned int)f2bf(r2) | ((unsigned int)f2bf(r3) << 16);
        out[(size_t)node * 32 + q] = o;
    }
}

// ---------------- agg layer 2 (64 ch, h3 PRE-SCALED): 1 node/wave, fp32 out ----------------

__global__ __launch_bounds__(256) void agg64_kernel(const int* __restrict__ rowptr,
                                                    const int* __restrict__ csr,
                                                    const float* __restrict__ dinv,
                                                    const unsigned int* __restrict__ H,
                                                    const float* __restrict__ b,
                                                    float2* __restrict__ out) {
    const int node = blockIdx.x * 4 + (threadIdx.x >> 6);
    const int half = (threadIdx.x >> 5) & 1;
    const int q = threadIdx.x & 31;

    float a0 = 0.f, a1 = 0.f;
    const int e0 = rowptr[node];
    const int cnt = rowptr[node + 1] - e0;
    const int base = e0 + half * 4;

    int k = 0;
    for (; k + 8 <= cnt; k += 8) {
        int i0 = csr[base + k];
        int i1 = csr[base + k + 1];
        int i2 = csr[base + k + 2];
        int i3 = csr[base + k + 3];
        unsigned int h0 = H[(size_t)i0 * 32 + q];
        unsigned int h1 = H[(size_t)i1 * 32 + q];
        unsigned int h2 = H[(size_t)i2 * 32 + q];
        unsigned int h3 = H[(size_t)i3 * 32 + q];
        a0 += bf2f((unsigned short)(h0 & 0xffff)) + bf2f((unsigned short)(h1 & 0xffff)) +
              bf2f((unsigned short)(h2 & 0xffff)) + bf2f((unsigned short)(h3 & 0xffff));
        a1 += bf2f((unsigned short)(h0 >> 16)) + bf2f((unsigned short)(h1 >> 16)) +
              bf2f((unsigned short)(h2 >> 16)) + bf2f((unsigned short)(h3 >> 16));
    }
    for (int j = k + half; j < cnt; j += 2) {
        int s = csr[e0 + j];
        unsigned int h = H[(size_t)s * 32 + q];
        a0 += bf2f((unsigned short)(h & 0xffff));
        a1 += bf2f((unsigned short)(h >> 16));
    }

    a0 += __shfl_xor(a0, 32);
    a1 += __shfl_xor(a1, 32);

    if (half == 0) {
        const float dn = dinv[node];
        unsigned int self = H[(size_t)node * 32 + q];
        float2 bb = *(const float2*)&b[q * 2];
        float r0 = fmaf(dn, bf2f((unsigned short)(self & 0xffff)) + a0, bb.x);
        float r1 = fmaf(dn, bf2f((unsigned short)(self >> 16)) + a1, bb.y);
        out[(size_t)node * 32 + q] = make_float2(r0, r1);
    }
}

// ---------------- launch ----------------

extern "C" void kernel_launch(void* const* d_in, const int* in_sizes, int n_in,
                              void* d_out, int out_size, void* d_ws, size_t ws_size,
                              hipStream_t stream) {
    const float* x  = (const float*)d_in[0];
    const int*   ei = (const int*)d_in[1];
    const float* W1 = (const float*)d_in[2];
    const float* b1 = (const float*)d_in[3];
    const float* W2 = (const float*)d_in[4];
    const float* b2 = (const float*)d_in[5];

    const int* src = ei;
    const int* dst = ei + N_EDGES;

    // workspace layout
    unsigned short* h1 = (unsigned short*)d_ws;                 // [N][128] bf16 (UNSCALED h1 / h3)
    unsigned short* h2 = h1 + (size_t)N_NODES * HID_C;          // [N][128] bf16 activations
    float* dinv   = (float*)(h2 + (size_t)N_NODES * HID_C);     // 50,048 f
    int*   degi   = (int*)(dinv + 50048);                       // 50,048 i (deg -> cursor)
    int*   rowptr = degi + 50048;                               // 50,001 i
    int*   csr    = rowptr + 50051;                             // 500,000 i
    unsigned int* state = (unsigned int*)(csr + 500000);        // 256 u (lookback state)
    unsigned short* h3 = h1;                                    // reuse h1: [N][64] bf16

    // 1) zero degree array + lookback state
    zero2_kernel<<<49, 256, 0, stream>>>((int4*)degi, (N_NODES + 3) / 4, (int4*)state, 64);

    // 2) GEMM1 (unscaled h1) FUSED with degree histogram (role-split, independent work)
    mfma_gemm<HID_C, false, false, true><<<NTILES + DEGB, 256, 0, stream>>>(
        x, W1, nullptr, h1, dst, degi);

    // 3) single-pass scan -> rowptr, cursor, dinv
    scanall_kernel<<<SCAN_NB, 256, 0, stream>>>(degi, rowptr, degi, dinv, state);

    // 4) CSR fill
    fill_kernel<<<(N_EDGES + 255) / 256, 256, 0, stream>>>(src, dst, degi, csr);

    // 5) agg layer 1 (per-edge dinv) -> h2
    agg128_kernel<<<N_NODES / 4, 256, 0, stream>>>(rowptr, csr, dinv, (const uint2*)h1, b1,
                                                   (uint2*)h2);

    // 6) GEMM2 (prescaled by dinv) -> h3
    mfma_gemm<OUT_C, true, true, false><<<NTILES, 256, 0, stream>>>(
        h2, W2, dinv, h3, nullptr, nullptr);

    // 7) agg layer 2 -> out (fp32)
    agg64_kernel<<<N_NODES / 4, 256, 0, stream>>>(rowptr, csr, dinv, (const unsigned int*)h3,
                                                  b2, (float2*)d_out);
}

// Round 15
// 128.442 us; speedup vs baseline: 1.1256x; 1.0843x over previous
//
#include <hip/hip_runtime.h>

#define N_NODES 50000
#define N_EDGES 500000
#define IN_C 128
#define HID_C 128
#define OUT_C 64

#define SCAN_NB 196            // (50000+255)/256
#define NTILES 782             // (50000+63)/64
#define FILLB 256              // fill blocks fused into gemm1 dispatch
#define SP 136                 // padded LDS row stride (shorts)

typedef short s16x8 __attribute__((ext_vector_type(8)));
typedef float f32x4 __attribute__((ext_vector_type(4)));

__device__ __forceinline__ unsigned short f2bf(float f) {
    unsigned int u = __float_as_uint(f);
    u = (u + 0x7FFF + ((u >> 16) & 1)) >> 16;  // round-to-nearest-even
    return (unsigned short)u;
}
__device__ __forceinline__ float bf2f(unsigned short u) {
    return __uint_as_float(((unsigned int)u) << 16);
}

// ---------------- zero ----------------

__global__ __launch_bounds__(256) void zero_kernel(int4* __restrict__ p, int n4) {
    int i = blockIdx.x * blockDim.x + threadIdx.x;
    if (i < n4) p[i] = make_int4(0, 0, 0, 0);
}

// ---------------- CSR build ----------------

__global__ void deg_kernel(const int* __restrict__ dst, int* __restrict__ degi) {
    int e = blockIdx.x * blockDim.x + threadIdx.x;
    if (e < N_EDGES) atomicAdd(&degi[dst[e]], 1);
}

__global__ __launch_bounds__(256) void scan1_kernel(const int* __restrict__ degi,
                                                    int* __restrict__ rowptr,
                                                    int* __restrict__ blocksum,
                                                    float* __restrict__ dinv) {
    __shared__ int sh[256];
    const int t = threadIdx.x;
    const int i = blockIdx.x * 256 + t;
    int v = (i < N_NODES) ? degi[i] : 0;
    sh[t] = v;
    __syncthreads();
#pragma unroll
    for (int off = 1; off < 256; off <<= 1) {
        int tmp = (t >= off) ? sh[t - off] : 0;
        __syncthreads();
        sh[t] += tmp;
        __syncthreads();
    }
    if (i < N_NODES) {
        rowptr[i] = sh[t];
        dinv[i] = rsqrtf((float)v + 1.0f);
    }
    if (t == 255) blocksum[blockIdx.x] = sh[255];
}

__global__ __launch_bounds__(256) void scan23_kernel(int* __restrict__ rowptr,
                                                     int* __restrict__ degi,
                                                     const int* __restrict__ blocksum) {
    __shared__ int sh[256];
    const int t = threadIdx.x;
    int v = (t < SCAN_NB) ? blocksum[t] : 0;
    sh[t] = v;
    __syncthreads();
#pragma unroll
    for (int off = 1; off < 256; off <<= 1) {
        int tmp = (t >= off) ? sh[t - off] : 0;
        __syncthreads();
        sh[t] += tmp;
        __syncthreads();
    }
    const int myoff = sh[blockIdx.x] - blocksum[blockIdx.x];
    const int i = blockIdx.x * 256 + t;
    if (i < N_NODES) {
        int d = degi[i];
        int ex = rowptr[i] - d + myoff;
        rowptr[i] = ex;
        degi[i] = ex;  // cursor for fill
    }
    if (i == 0) rowptr[N_NODES] = N_EDGES;
}

// ---------------- GEMM1 (prescaled h1') FUSED with CSR fill (role-split) ----------------
// Blocks [0,NTILES): h1[n,128](bf16) = dinv[n] * (x[n,128] @ W1). Blocks >= NTILES: fill.
// Both need only post-scan state (dinv / cursor); independent of each other -> one dispatch,
// fill (the bigger hideable job, ~12us) fully hidden under gemm1 (~14us).

__global__ __launch_bounds__(256) void gemm1_fill_kernel(const float* __restrict__ x,
                                                         const float* __restrict__ W,
                                                         const float* __restrict__ dinv,
                                                         unsigned short* __restrict__ H,
                                                         const int* __restrict__ src,
                                                         const int* __restrict__ dst,
                                                         int* __restrict__ cursor,
                                                         int* __restrict__ csr) {
    constexpr int NOUT = HID_C;
    constexpr int NT = NOUT / 64;
    __shared__ unsigned short Xl[64 * SP];
    const int tid = threadIdx.x;

    if (blockIdx.x >= NTILES) {
        for (int e = (blockIdx.x - NTILES) * 256 + tid; e < N_EDGES; e += FILLB * 256) {
            int d = dst[e];
            int pos = atomicAdd(&cursor[d], 1);
            csr[pos] = src[e];
        }
        return;
    }

    const int w = tid >> 6;
    const int lane = tid & 63;
    const int kk = lane >> 4;
    const int cl = lane & 15;
    const int row0 = blockIdx.x * 64;

    for (int c = tid; c < 64 * 32; c += 256) {
        int r = c >> 5, cc = c & 31;
        int gr = row0 + r;
        ushort4 o;
        if (gr < N_NODES) {
            float4 v = ((const float4*)x)[(size_t)gr * 32 + cc];
            o = make_ushort4(f2bf(v.x), f2bf(v.y), f2bf(v.z), f2bf(v.w));
        } else {
            o = make_ushort4(0, 0, 0, 0);
        }
        *(ushort4*)&Xl[r * SP + cc * 4] = o;
    }

    s16x8 bfrag[NT][4];
#pragma unroll
    for (int i = 0; i < NT; i++) {
        int colg = (w * NT + i) * 16 + cl;
#pragma unroll
        for (int s = 0; s < 4; s++)
#pragma unroll
            for (int j = 0; j < 8; j++)
                bfrag[i][s][j] = (short)f2bf(W[(s * 32 + kk * 8 + j) * NOUT + colg]);
    }

    __syncthreads();

    f32x4 acc[4][NT];
#pragma unroll
    for (int rt = 0; rt < 4; rt++)
#pragma unroll
        for (int i = 0; i < NT; i++) acc[rt][i] = (f32x4){0.f, 0.f, 0.f, 0.f};

#pragma unroll
    for (int rt = 0; rt < 4; rt++) {
        const int rl = rt * 16 + cl;
        s16x8 a[4];
#pragma unroll
        for (int s = 0; s < 4; s++)
            a[s] = *(const s16x8*)&Xl[rl * SP + s * 32 + kk * 8];
#pragma unroll
        for (int i = 0; i < NT; i++)
#pragma unroll
            for (int s = 0; s < 4; s++)
                acc[rt][i] = __builtin_amdgcn_mfma_f32_16x16x32_bf16(a[s], bfrag[i][s],
                                                                     acc[rt][i], 0, 0, 0);
    }

#pragma unroll
    for (int rt = 0; rt < 4; rt++) {
        float4 dv = *(const float4*)&dinv[row0 + rt * 16 + kk * 4];
        float dvv[4] = {dv.x, dv.y, dv.z, dv.w};
#pragma unroll
        for (int i = 0; i < NT; i++) {
            int colg = (w * NT + i) * 16 + cl;
#pragma unroll
            for (int r = 0; r < 4; r++) {
                int rowg = row0 + rt * 16 + kk * 4 + r;
                if (rowg < N_NODES)
                    H[(size_t)rowg * NOUT + colg] = f2bf(dvv[r] * acc[rt][i][r]);
            }
        }
    }
}

// ---------------- GEMM2: h3[n,64](bf16) = dinv[n] * (h2[n,128] @ W2) ----------------

__global__ __launch_bounds__(256) void gemm2_kernel(const unsigned short* __restrict__ h2,
                                                    const float* __restrict__ W,
                                                    const float* __restrict__ dinv,
                                                    unsigned short* __restrict__ H) {
    constexpr int NOUT = OUT_C;
    __shared__ unsigned short Xl[64 * SP];
    const int tid = threadIdx.x;
    const int w = tid >> 6;
    const int lane = tid & 63;
    const int kk = lane >> 4;
    const int cl = lane & 15;
    const int row0 = blockIdx.x * 64;

    for (int c = tid; c < 64 * 32; c += 256) {
        int r = c >> 5, cc = c & 31;
        int gr = row0 + r;
        ushort4 o = (gr < N_NODES) ? ((const ushort4*)h2)[(size_t)gr * 32 + cc]
                                   : make_ushort4(0, 0, 0, 0);
        *(ushort4*)&Xl[r * SP + cc * 4] = o;
    }

    s16x8 bfrag[4];
#pragma unroll
    for (int s = 0; s < 4; s++)
#pragma unroll
        for (int j = 0; j < 8; j++)
            bfrag[s][j] = (short)f2bf(W[(s * 32 + kk * 8 + j) * NOUT + w * 16 + cl]);

    __syncthreads();

    f32x4 acc[4];
#pragma unroll
    for (int rt = 0; rt < 4; rt++) acc[rt] = (f32x4){0.f, 0.f, 0.f, 0.f};

#pragma unroll
    for (int rt = 0; rt < 4; rt++) {
        const int rl = rt * 16 + cl;
        s16x8 a[4];
#pragma unroll
        for (int s = 0; s < 4; s++)
            a[s] = *(const s16x8*)&Xl[rl * SP + s * 32 + kk * 8];
#pragma unroll
        for (int s = 0; s < 4; s++)
            acc[rt] = __builtin_amdgcn_mfma_f32_16x16x32_bf16(a[s], bfrag[s], acc[rt], 0, 0, 0);
    }

#pragma unroll
    for (int rt = 0; rt < 4; rt++) {
        float4 dv = *(const float4*)&dinv[row0 + rt * 16 + kk * 4];
        float dvv[4] = {dv.x, dv.y, dv.z, dv.w};
        int colg = w * 16 + cl;
#pragma unroll
        for (int r = 0; r < 4; r++) {
            int rowg = row0 + rt * 16 + kk * 4 + r;
            if (rowg < N_NODES)
                H[(size_t)rowg * NOUT + colg] = f2bf(dvv[r] * acc[rt][r]);
        }
    }
}

// ---------------- agg layer 1 (128 ch, h1 PRE-SCALED): 1 node/wave, half-wave split ----------------
// out[n][c] = relu( dinv[n]*(h1'[n][c] + sum_s h1'[s][c]) + b[c] )

__global__ __launch_bounds__(256) void agg128_kernel(const int* __restrict__ rowptr,
                                                     const int* __restrict__ csr,
                                                     const float* __restrict__ dinv,
                                                     const uint2* __restrict__ H,
                                                     const float* __restrict__ b,
                                                     uint2* __restrict__ out) {
    const int node = blockIdx.x * 4 + (threadIdx.x >> 6);
    const int half = (threadIdx.x >> 5) & 1;
    const int q = threadIdx.x & 31;

    float a0 = 0.f, a1 = 0.f, a2 = 0.f, a3 = 0.f;
    const int e0 = rowptr[node];
    const int cnt = rowptr[node + 1] - e0;
    const int base = e0 + half * 4;

    int k = 0;
    for (; k + 8 <= cnt; k += 8) {  // 8 edges/iter, 4 per half
        int i0 = csr[base + k];
        int i1 = csr[base + k + 1];
        int i2 = csr[base + k + 2];
        int i3 = csr[base + k + 3];
        uint2 h0 = H[(size_t)i0 * 32 + q];
        uint2 h1v = H[(size_t)i1 * 32 + q];
        uint2 h2v = H[(size_t)i2 * 32 + q];
        uint2 h3v = H[(size_t)i3 * 32 + q];
        a0 += bf2f((unsigned short)(h0.x & 0xffff)) + bf2f((unsigned short)(h1v.x & 0xffff)) +
              bf2f((unsigned short)(h2v.x & 0xffff)) + bf2f((unsigned short)(h3v.x & 0xffff));
        a1 += bf2f((unsigned short)(h0.x >> 16)) + bf2f((unsigned short)(h1v.x >> 16)) +
              bf2f((unsigned short)(h2v.x >> 16)) + bf2f((unsigned short)(h3v.x >> 16));
        a2 += bf2f((unsigned short)(h0.y & 0xffff)) + bf2f((unsigned short)(h1v.y & 0xffff)) +
              bf2f((unsigned short)(h2v.y & 0xffff)) + bf2f((unsigned short)(h3v.y & 0xffff));
        a3 += bf2f((unsigned short)(h0.y >> 16)) + bf2f((unsigned short)(h1v.y >> 16)) +
              bf2f((unsigned short)(h2v.y >> 16)) + bf2f((unsigned short)(h3v.y >> 16));
    }
    for (int j = k + half; j < cnt; j += 2) {  // tail: 2 edges/iter (1 per half)
        int s = csr[e0 + j];
        uint2 h = H[(size_t)s * 32 + q];
        a0 += bf2f((unsigned short)(h.x & 0xffff));
        a1 += bf2f((unsigned short)(h.x >> 16));
        a2 += bf2f((unsigned short)(h.y & 0xffff));
        a3 += bf2f((unsigned short)(h.y >> 16));
    }

    a0 += __shfl_xor(a0, 32);
    a1 += __shfl_xor(a1, 32);
    a2 += __shfl_xor(a2, 32);
    a3 += __shfl_xor(a3, 32);

    if (half == 0) {
        const float dn = dinv[node];
        uint2 self = H[(size_t)node * 32 + q];
        float4 bb = *(const float4*)&b[q * 4];
        float r0 = fmaf(dn, bf2f((unsigned short)(self.x & 0xffff)) + a0, bb.x);
        float r1 = fmaf(dn, bf2f((unsigned short)(self.x >> 16)) + a1, bb.y);
        float r2 = fmaf(dn, bf2f((unsigned short)(self.y & 0xffff)) + a2, bb.z);
        float r3 = fmaf(dn, bf2f((unsigned short)(self.y >> 16)) + a3, bb.w);
        r0 = fmaxf(r0, 0.f);
        r1 = fmaxf(r1, 0.f);
        r2 = fmaxf(r2, 0.f);
        r3 = fmaxf(r3, 0.f);
        uint2 o;
        o.x = (unsigned int)f2bf(r0) | ((unsigned int)f2bf(r1) << 16);
        o.y = (unsigned int)f2bf(r2) | ((unsigned int)f2bf(r3) << 16);
        out[(size_t)node * 32 + q] = o;
    }
}

// ---------------- agg layer 2 (64 ch, h3 PRE-SCALED): 1 node/wave, fp32 out ----------------

__global__ __launch_bounds__(256) void agg64_kernel(const int* __restrict__ rowptr,
                                                    const int* __restrict__ csr,
                                                    const float* __restrict__ dinv,
                                                    const unsigned int* __restrict__ H,
                                                    const float* __restrict__ b,
                                                    float2* __restrict__ out) {
    const int node = blockIdx.x * 4 + (threadIdx.x >> 6);
    const int half = (threadIdx.x >> 5) & 1;
    const int q = threadIdx.x & 31;

    float a0 = 0.f, a1 = 0.f;
    const int e0 = rowptr[node];
    const int cnt = rowptr[node + 1] - e0;
    const int base = e0 + half * 4;

    int k = 0;
    for (; k + 8 <= cnt; k += 8) {
        int i0 = csr[base + k];
        int i1 = csr[base + k + 1];
        int i2 = csr[base + k + 2];
        int i3 = csr[base + k + 3];
        unsigned int h0 = H[(size_t)i0 * 32 + q];
        unsigned int h1 = H[(size_t)i1 * 32 + q];
        unsigned int h2 = H[(size_t)i2 * 32 + q];
        unsigned int h3 = H[(size_t)i3 * 32 + q];
        a0 += bf2f((unsigned short)(h0 & 0xffff)) + bf2f((unsigned short)(h1 & 0xffff)) +
              bf2f((unsigned short)(h2 & 0xffff)) + bf2f((unsigned short)(h3 & 0xffff));
        a1 += bf2f((unsigned short)(h0 >> 16)) + bf2f((unsigned short)(h1 >> 16)) +
              bf2f((unsigned short)(h2 >> 16)) + bf2f((unsigned short)(h3 >> 16));
    }
    for (int j = k + half; j < cnt; j += 2) {
        int s = csr[e0 + j];
        unsigned int h = H[(size_t)s * 32 + q];
        a0 += bf2f((unsigned short)(h & 0xffff));
        a1 += bf2f((unsigned short)(h >> 16));
    }

    a0 += __shfl_xor(a0, 32);
    a1 += __shfl_xor(a1, 32);

    if (half == 0) {
        const float dn = dinv[node];
        unsigned int self = H[(size_t)node * 32 + q];
        float2 bb = *(const float2*)&b[q * 2];
        float r0 = fmaf(dn, bf2f((unsigned short)(self & 0xffff)) + a0, bb.x);
        float r1 = fmaf(dn, bf2f((unsigned short)(self >> 16)) + a1, bb.y);
        out[(size_t)node * 32 + q] = make_float2(r0, r1);
    }
}

// ---------------- launch ----------------

extern "C" void kernel_launch(void* const* d_in, const int* in_sizes, int n_in,
                              void* d_out, int out_size, void* d_ws, size_t ws_size,
                              hipStream_t stream) {
    const float* x  = (const float*)d_in[0];
    const int*   ei = (const int*)d_in[1];
    const float* W1 = (const float*)d_in[2];
    const float* b1 = (const float*)d_in[3];
    const float* W2 = (const float*)d_in[4];
    const float* b2 = (const float*)d_in[5];

    const int* src = ei;
    const int* dst = ei + N_EDGES;

    // workspace layout
    unsigned short* h1 = (unsigned short*)d_ws;                 // [N][128] bf16 (prescaled h1')
    unsigned short* h2 = h1 + (size_t)N_NODES * HID_C;          // [N][128] bf16 activations
    float* dinv   = (float*)(h2 + (size_t)N_NODES * HID_C);     // 50,048 f
    int*   degi   = (int*)(dinv + 50048);                       // 50,048 i (deg -> cursor)
    int*   rowptr = degi + 50048;                               // 50,001 i
    int*   csr    = rowptr + 50051;                             // 500,000 i
    int*   bsum   = csr + 500000;                               // 256 i
    unsigned short* h3 = h1;                                    // reuse h1: [N][64] bf16

    // 1) zero degree array
    zero_kernel<<<49, 256, 0, stream>>>((int4*)degi, (N_NODES + 3) / 4);
    // 2) degree histogram
    deg_kernel<<<(N_EDGES + 255) / 256, 256, 0, stream>>>(dst, degi);
    // 3-4) scan -> rowptr, dinv, cursor
    scan1_kernel<<<SCAN_NB, 256, 0, stream>>>(degi, rowptr, bsum, dinv);
    scan23_kernel<<<SCAN_NB, 256, 0, stream>>>(rowptr, degi, bsum);
    // 5) GEMM1 (prescaled h1') || CSR fill — role-split fused
    gemm1_fill_kernel<<<NTILES + FILLB, 256, 0, stream>>>(x, W1, dinv, h1, src, dst, degi, csr);
    // 6) agg layer 1 -> h2 (bf16)
    agg128_kernel<<<N_NODES / 4, 256, 0, stream>>>(rowptr, csr, dinv, (const uint2*)h1, b1,
                                                   (uint2*)h2);
    // 7) GEMM2 (prescaled) -> h3'
    gemm2_kernel<<<NTILES, 256, 0, stream>>>(h2, W2, dinv, h3);
    // 8) agg layer 2 -> out (fp32)
    agg64_kernel<<<N_NODES / 4, 256, 0, stream>>>(rowptr, csr, dinv, (const unsigned int*)h3,
                                                  b2, (float2*)d_out);
}